// Round 1
// baseline (753.396 us; speedup 1.0000x reference)
//
#include <hip/hip_runtime.h>
#include <hip/hip_bf16.h>

// MoE top-2 layer, MI355X. Sparse routing: only 8192 (token,expert) pairs
// of 32768 dense ones are computed. fp16 MFMA (16x16x32) with fp32 accum.
//
// Sizes (fixed by the reference): N=4096 tokens, C=1024, E=8, H=4096, K=2.
// NPC = 9216 = worst-case slot capacity with per-expert 128-alignment.

#define NTOK  4096
#define CDIM  1024
#define HDIM  4096
#define NEXP  8
#define NPC   9216
#define MAXMT 72
#define LDK   40   // padded LDS k-stride (elements): 80 B rows, 2-way-max banks

typedef _Float16 half8 __attribute__((ext_vector_type(8)));
typedef float    f32x4 __attribute__((ext_vector_type(4)));

__device__ __forceinline__ float gelu_new(float x) {
    const float c = 0.7978845608028654f;  // sqrt(2/pi)
    return 0.5f * x * (1.0f + tanhf(c * (x + 0.044715f * x * x * x)));
}

// ---------------- utility kernels ----------------

__global__ void zero_u32(unsigned int* __restrict__ p, int n) {
    int i = blockIdx.x * 256 + threadIdx.x;
    if (i < n) p[i] = 0u;
}

__global__ void cvt_x_kernel(const float* __restrict__ x, _Float16* __restrict__ xh) {
    int i = (blockIdx.x * 256 + threadIdx.x) * 8;  // total elems = 4194304
    float4 a = *(const float4*)(x + i);
    float4 b = *(const float4*)(x + i + 4);
    half8 o;
    o[0] = (_Float16)a.x; o[1] = (_Float16)a.y; o[2] = (_Float16)a.z; o[3] = (_Float16)a.w;
    o[4] = (_Float16)b.x; o[5] = (_Float16)b.y; o[6] = (_Float16)b.z; o[7] = (_Float16)b.w;
    *(half8*)(xh + i) = o;
}

// ---------------- routing ----------------

// One wave per token: 8 dot products over C, shuffle-reduce, top-2.
// top-2 by logits == top-2 by softmax probs; renormalized gates are
// w0 = 1/(1+e^{l1-l0}), w1 = 1-w0 (stable since l0 >= l1).
__global__ __launch_bounds__(256) void router_kernel(
    const float* __restrict__ x, const float* __restrict__ rw,
    int* __restrict__ tok_e, float* __restrict__ tok_w, int* __restrict__ counts)
{
    int wave = threadIdx.x >> 6, lane = threadIdx.x & 63;
    int n = blockIdx.x * 4 + wave;
    const float* xr = x + (size_t)n * CDIM;
    float acc[NEXP];
    #pragma unroll
    for (int e = 0; e < NEXP; ++e) acc[e] = 0.f;
    for (int c = lane; c < CDIM; c += 64) {
        float xv = xr[c];
        #pragma unroll
        for (int e = 0; e < NEXP; ++e) acc[e] = fmaf(xv, rw[e * CDIM + c], acc[e]);
    }
    #pragma unroll
    for (int e = 0; e < NEXP; ++e) {
        float v = acc[e];
        #pragma unroll
        for (int off = 32; off > 0; off >>= 1) v += __shfl_down(v, off);
        acc[e] = v;
    }
    if (lane == 0) {
        float l0 = -3.0e38f, l1 = -3.0e38f; int b0 = 0, b1 = 0;
        #pragma unroll
        for (int e = 0; e < NEXP; ++e) {
            float v = acc[e];
            if (v > l0)      { l1 = l0; b1 = b0; l0 = v; b0 = e; }
            else if (v > l1) { l1 = v; b1 = e; }
        }
        float t  = __expf(l1 - l0) ;
        // use accurate expf for safety:
        t = expf(l1 - l0);
        float w0 = 1.f / (1.f + t);
        float w1 = t  / (1.f + t);
        tok_e[n * 2]     = b0;  tok_e[n * 2 + 1] = b1;
        tok_w[n * 2]     = w0;  tok_w[n * 2 + 1] = w1;
        atomicAdd(&counts[b0], 1);
        atomicAdd(&counts[b1], 1);
    }
}

// Single-thread plan: 128-aligned per-expert slot bases, tile->expert map.
__global__ void plan_kernel(const int* __restrict__ counts, int* __restrict__ cursors,
                            int* __restrict__ mtiles, int* __restrict__ tile_expert)
{
    if (threadIdx.x == 0 && blockIdx.x == 0) {
        int b = 0;
        for (int e = 0; e < NEXP; ++e) {
            cursors[e] = b;
            int tiles = (counts[e] + 127) >> 7;
            for (int t = 0; t < tiles; ++t) tile_expert[(b >> 7) + t] = e;
            b += tiles << 7;
        }
        *mtiles = b >> 7;
        for (int t = b >> 7; t < MAXMT; ++t) tile_expert[t] = 0;
    }
}

__global__ void assign_kernel(const int* __restrict__ tok_e, const float* __restrict__ tok_w,
                              int* __restrict__ cursors,
                              int* __restrict__ pair_tok, float* __restrict__ pair_gate)
{
    int n = blockIdx.x * 256 + threadIdx.x;  // exactly NTOK threads
    #pragma unroll
    for (int k = 0; k < 2; ++k) {
        int e = tok_e[n * 2 + k];
        int slot = atomicAdd(&cursors[e], 1);
        pair_tok[slot]  = n;
        pair_gate[slot] = tok_w[n * 2 + k];
    }
}

// ---------------- GEMM 1: h = gelu(gather(x) @ w_fc[e] + b_fc[e]) ----------------
// 128x128 tile, BK=32, 4 waves each computing 64x64 via 4x4 mfma_f32_16x16x32_f16.
// A: gathered token rows from xh (fp16, k-contiguous -> ds 16B loads).
// B: w_fc[e] is [K=C][N=H] fp32 -> staged transposed+converted to LDS [n][k-pack].

__global__ __launch_bounds__(256) void gemm_fc_kernel(
    const _Float16* __restrict__ xh,    // [NTOK, CDIM]
    const float*    __restrict__ w_fc,  // [E, CDIM, HDIM]
    const float*    __restrict__ b_fc,  // [E, HDIM]
    const int*      __restrict__ pair_tok,
    const int*      __restrict__ tile_expert,
    const int*      __restrict__ mtiles,
    _Float16*       __restrict__ hb)    // [NPC, HDIM]
{
    const int mt = blockIdx.y;
    if (mt >= *mtiles) return;
    const int nt = blockIdx.x;
    const int e  = tile_expert[mt];
    const int m0 = mt << 7, n0 = nt << 7;

    __shared__ _Float16 As[128 * LDK];
    __shared__ _Float16 Bs[128 * LDK];

    const int tid = threadIdx.x;
    const int lane = tid & 63, wv = tid >> 6;
    const int wm = (wv >> 1) * 64, wn = (wv & 1) * 64;
    const int l16 = lane & 15, lq = lane >> 4;

    // A staging: thread -> (row, 8-elem chunk); 2 rows per thread
    const int arow = tid >> 2;
    const int ach  = (tid & 3) * 8;
    const int tok0 = pair_tok[m0 + arow];
    const int tok1 = pair_tok[m0 + arow + 64];
    const _Float16* asrc0 = xh + (size_t)tok0 * CDIM + ach;
    const _Float16* asrc1 = xh + (size_t)tok1 * CDIM + ach;

    // B staging: thread -> (n in [0,128), 16 consecutive k)
    const int nloc = tid & 127;
    const int kg   = (tid >> 7) * 16;   // 0 or 16
    const float* bsrc = w_fc + ((size_t)e * CDIM + kg) * HDIM + n0 + nloc;

    f32x4 acc[4][4];
    #pragma unroll
    for (int i = 0; i < 4; ++i)
        #pragma unroll
        for (int j = 0; j < 4; ++j) { acc[i][j][0]=0.f; acc[i][j][1]=0.f; acc[i][j][2]=0.f; acc[i][j][3]=0.f; }

    for (int k0 = 0; k0 < CDIM; k0 += 32) {
        *(half8*)&As[arow * LDK + ach]        = *(const half8*)(asrc0 + k0);
        *(half8*)&As[(arow + 64) * LDK + ach] = *(const half8*)(asrc1 + k0);
        const float* bs = bsrc + (size_t)k0 * HDIM;
        #pragma unroll
        for (int h = 0; h < 2; ++h) {
            half8 pk;
            #pragma unroll
            for (int j = 0; j < 8; ++j) pk[j] = (_Float16)bs[(size_t)(h * 8 + j) * HDIM];
            *(half8*)&Bs[nloc * LDK + kg + h * 8] = pk;
        }
        __syncthreads();
        half8 af[4], bfv[4];
        #pragma unroll
        for (int i = 0; i < 4; ++i) af[i]  = *(const half8*)&As[(wm + i * 16 + l16) * LDK + lq * 8];
        #pragma unroll
        for (int j = 0; j < 4; ++j) bfv[j] = *(const half8*)&Bs[(wn + j * 16 + l16) * LDK + lq * 8];
        #pragma unroll
        for (int i = 0; i < 4; ++i)
            #pragma unroll
            for (int j = 0; j < 4; ++j)
                acc[i][j] = __builtin_amdgcn_mfma_f32_16x16x32_f16(af[i], bfv[j], acc[i][j], 0, 0, 0);
        __syncthreads();
    }

    float bias[4];
    #pragma unroll
    for (int j = 0; j < 4; ++j) bias[j] = b_fc[e * HDIM + n0 + wn + j * 16 + l16];
    #pragma unroll
    for (int i = 0; i < 4; ++i) {
        #pragma unroll
        for (int r = 0; r < 4; ++r) {
            int slot = m0 + wm + i * 16 + lq * 4 + r;  // D row = quad*4 + reg
            _Float16* dst = hb + (size_t)slot * HDIM + n0 + wn + l16;  // D col = lane&15
            #pragma unroll
            for (int j = 0; j < 4; ++j)
                dst[j * 16] = (_Float16)gelu_new(acc[i][j][r] + bias[j]);
        }
    }
}

// ---------------- GEMM 2: y[tok] += gate * (h @ w_proj[e] + b_proj[e]) ----------------

__global__ __launch_bounds__(256) void gemm_proj_kernel(
    const _Float16* __restrict__ hb,     // [NPC, HDIM]
    const float*    __restrict__ w_proj, // [E, HDIM, CDIM]
    const float*    __restrict__ b_proj, // [E, CDIM]
    const int*      __restrict__ pair_tok,
    const float*    __restrict__ pair_gate,
    const int*      __restrict__ tile_expert,
    const int*      __restrict__ mtiles,
    float*          __restrict__ y)      // [NTOK, CDIM]
{
    const int mt = blockIdx.y;
    if (mt >= *mtiles) return;
    const int nt = blockIdx.x;
    const int e  = tile_expert[mt];
    const int m0 = mt << 7, n0 = nt << 7;

    __shared__ _Float16 As[128 * LDK];
    __shared__ _Float16 Bs[128 * LDK];

    const int tid = threadIdx.x;
    const int lane = tid & 63, wv = tid >> 6;
    const int wm = (wv >> 1) * 64, wn = (wv & 1) * 64;
    const int l16 = lane & 15, lq = lane >> 4;

    const int arow = tid >> 2;
    const int ach  = (tid & 3) * 8;
    const _Float16* asrc0 = hb + (size_t)(m0 + arow) * HDIM + ach;
    const _Float16* asrc1 = hb + (size_t)(m0 + arow + 64) * HDIM + ach;

    const int nloc = tid & 127;
    const int kg   = (tid >> 7) * 16;
    const float* bsrc = w_proj + ((size_t)e * HDIM + kg) * CDIM + n0 + nloc;

    f32x4 acc[4][4];
    #pragma unroll
    for (int i = 0; i < 4; ++i)
        #pragma unroll
        for (int j = 0; j < 4; ++j) { acc[i][j][0]=0.f; acc[i][j][1]=0.f; acc[i][j][2]=0.f; acc[i][j][3]=0.f; }

    for (int k0 = 0; k0 < HDIM; k0 += 32) {
        *(half8*)&As[arow * LDK + ach]        = *(const half8*)(asrc0 + k0);
        *(half8*)&As[(arow + 64) * LDK + ach] = *(const half8*)(asrc1 + k0);
        const float* bs = bsrc + (size_t)k0 * CDIM;
        #pragma unroll
        for (int h = 0; h < 2; ++h) {
            half8 pk;
            #pragma unroll
            for (int j = 0; j < 8; ++j) pk[j] = (_Float16)bs[(size_t)(h * 8 + j) * CDIM];
            *(half8*)&Bs[nloc * LDK + kg + h * 8] = pk;
        }
        __syncthreads();
        half8 af[4], bfv[4];
        #pragma unroll
        for (int i = 0; i < 4; ++i) af[i]  = *(const half8*)&As[(wm + i * 16 + l16) * LDK + lq * 8];
        #pragma unroll
        for (int j = 0; j < 4; ++j) bfv[j] = *(const half8*)&Bs[(wn + j * 16 + l16) * LDK + lq * 8];
        #pragma unroll
        for (int i = 0; i < 4; ++i)
            #pragma unroll
            for (int j = 0; j < 4; ++j)
                acc[i][j] = __builtin_amdgcn_mfma_f32_16x16x32_f16(af[i], bfv[j], acc[i][j], 0, 0, 0);
        __syncthreads();
    }

    float bias[4];
    #pragma unroll
    for (int j = 0; j < 4; ++j) bias[j] = b_proj[e * CDIM + n0 + wn + j * 16 + l16];
    #pragma unroll
    for (int i = 0; i < 4; ++i) {
        #pragma unroll
        for (int r = 0; r < 4; ++r) {
            int slot = m0 + wm + i * 16 + lq * 4 + r;
            float g  = pair_gate[slot];
            if (g != 0.0f) {
                int tok = pair_tok[slot];
                float* dst = y + (size_t)tok * CDIM + n0 + wn + l16;
                #pragma unroll
                for (int j = 0; j < 4; ++j)
                    atomicAdd(&dst[j * 16], (acc[i][j][r] + bias[j]) * g);
            }
        }
    }
}

// ---------------- launch ----------------

extern "C" void kernel_launch(void* const* d_in, const int* in_sizes, int n_in,
                              void* d_out, int out_size, void* d_ws, size_t ws_size,
                              hipStream_t stream) {
    const float* x   = (const float*)d_in[0];
    const float* rw  = (const float*)d_in[1];
    const float* wfc = (const float*)d_in[2];
    const float* bfc = (const float*)d_in[3];
    const float* wpj = (const float*)d_in[4];
    const float* bpj = (const float*)d_in[5];
    float* y = (float*)d_out;

    char* ws = (char*)d_ws;
    // workspace layout (bytes)
    _Float16* xh        = (_Float16*)(ws);                       //  8,388,608
    _Float16* hb        = (_Float16*)(ws + 8388608);             // 75,497,472
    int*      pair_tok  = (int*)     (ws + 83886080);            //     36,864
    float*    pair_gate = (float*)   (ws + 83922944);            //     36,864
    int*      tok_e     = (int*)     (ws + 83959808);            //     32,768
    float*    tok_w     = (float*)   (ws + 83992576);            //     32,768
    int*      counts    = (int*)     (ws + 84025344);            // 8 ints
    int*      cursors   = counts + 8;                            // 8 ints
    int*      mtiles    = cursors + 8;                           // 1 int (+pad)
    int*      tile_expert = mtiles + 2;                          // 72 ints

    zero_u32<<<36, 256, 0, stream>>>((unsigned int*)pair_tok, NPC);
    zero_u32<<<36, 256, 0, stream>>>((unsigned int*)pair_gate, NPC);
    zero_u32<<<1, 256, 0, stream>>>((unsigned int*)counts, NEXP);
    zero_u32<<<16384, 256, 0, stream>>>((unsigned int*)y, NTOK * CDIM);

    cvt_x_kernel<<<2048, 256, 0, stream>>>(x, xh);
    router_kernel<<<1024, 256, 0, stream>>>(x, rw, tok_e, tok_w, counts);
    plan_kernel<<<1, 64, 0, stream>>>(counts, cursors, mtiles, tile_expert);
    assign_kernel<<<16, 256, 0, stream>>>(tok_e, tok_w, cursors, pair_tok, pair_gate);

    gemm_fc_kernel<<<dim3(HDIM / 128, MAXMT), 256, 0, stream>>>(
        xh, wfc, bfc, pair_tok, tile_expert, mtiles, hb);
    gemm_proj_kernel<<<dim3(CDIM / 128, MAXMT), 256, 0, stream>>>(
        hb, wpj, bpj, pair_tok, pair_gate, tile_expert, mtiles, y);
}

// Round 2
// 735.724 us; speedup vs baseline: 1.0240x; 1.0240x over previous
//
#include <hip/hip_runtime.h>

// MoE top-2 layer, MI355X — round 2: m97-style GEMMs.
// All GEMM operands pre-packed fp16 in [kb][row][32] layout (kb = k/32) so
// every 128x32 tile is one contiguous 8KB block -> global_load_lds width=16
// for BOTH operands. Weight fp16 transpose-convert costs the same HBM traffic
// as a plain convert (which we'd need anyway for MFMA).
//
// N=4096 tokens, C=1024, E=8, H=4096, top-2. NPC=9216 slot capacity
// (worst-case per-expert 128-alignment). ws required ~162 MB.

#define NTOK  4096
#define CDIM  1024
#define HDIM  4096
#define NEXP  8
#define NPC   9216
#define MAXMT 72
#define KB_C  32     // CDIM/32
#define KB_H  128    // HDIM/32

typedef _Float16 half8 __attribute__((ext_vector_type(8)));
typedef float    f32x4 __attribute__((ext_vector_type(4)));

// async global->LDS, 16B per lane. LDS dest = wave-uniform base + lane*16.
#define ASYNC_CP16(gp, lp)                                                         \
  __builtin_amdgcn_global_load_lds(                                                \
      (const __attribute__((address_space(1))) unsigned int*)(gp),                 \
      (__attribute__((address_space(3))) unsigned int*)(lp), 16, 0, 0)

__device__ __forceinline__ float gelu_new(float x) {
    const float c = 0.7978845608028654f;  // sqrt(2/pi)
    return 0.5f * x * (1.0f + tanhf(c * (x + 0.044715f * x * x * x)));
}

// ---------------- utility ----------------

__global__ void zero_u32(unsigned int* __restrict__ p, int n) {
    int i = blockIdx.x * 256 + threadIdx.x;
    if (i < n) p[i] = 0u;
}

// ---------------- routing ----------------

__global__ __launch_bounds__(256) void router_kernel(
    const float* __restrict__ x, const float* __restrict__ rw,
    int* __restrict__ tok_e, float* __restrict__ tok_w, int* __restrict__ counts)
{
    int wave = threadIdx.x >> 6, lane = threadIdx.x & 63;
    int n = blockIdx.x * 4 + wave;
    const float* xr = x + (size_t)n * CDIM;
    float acc[NEXP];
    #pragma unroll
    for (int e = 0; e < NEXP; ++e) acc[e] = 0.f;
    for (int c = lane; c < CDIM; c += 64) {
        float xv = xr[c];
        #pragma unroll
        for (int e = 0; e < NEXP; ++e) acc[e] = fmaf(xv, rw[e * CDIM + c], acc[e]);
    }
    #pragma unroll
    for (int e = 0; e < NEXP; ++e) {
        float v = acc[e];
        #pragma unroll
        for (int off = 32; off > 0; off >>= 1) v += __shfl_down(v, off);
        acc[e] = v;
    }
    if (lane == 0) {
        float l0 = -3.0e38f, l1 = -3.0e38f; int b0 = 0, b1 = 0;
        #pragma unroll
        for (int e = 0; e < NEXP; ++e) {
            float v = acc[e];
            if (v > l0)      { l1 = l0; b1 = b0; l0 = v; b0 = e; }
            else if (v > l1) { l1 = v; b1 = e; }
        }
        float t  = expf(l1 - l0);            // l1 <= l0, stable
        float w0 = 1.f / (1.f + t);
        float w1 = t  / (1.f + t);
        tok_e[n * 2]     = b0;  tok_e[n * 2 + 1] = b1;
        tok_w[n * 2]     = w0;  tok_w[n * 2 + 1] = w1;
        atomicAdd(&counts[b0], 1);
        atomicAdd(&counts[b1], 1);
    }
}

__global__ void plan_kernel(const int* __restrict__ counts, int* __restrict__ cursors,
                            int* __restrict__ mtiles, int* __restrict__ tile_expert)
{
    if (threadIdx.x == 0 && blockIdx.x == 0) {
        int b = 0;
        for (int e = 0; e < NEXP; ++e) {
            cursors[e] = b;
            int tiles = (counts[e] + 127) >> 7;
            for (int t = 0; t < tiles; ++t) tile_expert[(b >> 7) + t] = e;
            b += tiles << 7;
        }
        *mtiles = b >> 7;
        for (int t = b >> 7; t < MAXMT; ++t) tile_expert[t] = 0;
    }
}

__global__ void assign_kernel(const int* __restrict__ tok_e, const float* __restrict__ tok_w,
                              int* __restrict__ cursors,
                              int* __restrict__ pair_tok, float* __restrict__ pair_gate)
{
    int n = blockIdx.x * 256 + threadIdx.x;  // exactly NTOK threads
    #pragma unroll
    for (int k = 0; k < 2; ++k) {
        int e = tok_e[n * 2 + k];
        int slot = atomicAdd(&cursors[e], 1);
        pair_tok[slot]  = n;
        pair_gate[slot] = tok_w[n * 2 + k];
    }
}

// ---------------- A gather+convert into packed layout ----------------
// xg[kb][slot][kk] = fp16(x[pair_tok[slot]][kb*32+kk]); pad slots -> token 0.

__global__ __launch_bounds__(256) void gather_x_kernel(
    const float* __restrict__ x, const int* __restrict__ pair_tok,
    _Float16* __restrict__ xg)
{
    int o = blockIdx.x * 256 + threadIdx.x;          // KB_C * NPC * 4 threads
    int kb   = o / (NPC * 4);
    int rem  = o - kb * (NPC * 4);
    int slot = rem >> 2;
    int c    = (rem & 3) * 8;
    int tok  = pair_tok[slot];
    const float* src = x + (size_t)tok * CDIM + kb * 32 + c;
    float4 a = *(const float4*)src;
    float4 b = *(const float4*)(src + 4);
    half8 h;
    h[0] = (_Float16)a.x; h[1] = (_Float16)a.y; h[2] = (_Float16)a.z; h[3] = (_Float16)a.w;
    h[4] = (_Float16)b.x; h[5] = (_Float16)b.y; h[6] = (_Float16)b.z; h[7] = (_Float16)b.w;
    *(half8*)(xg + ((size_t)kb * NPC + slot) * 32 + c) = h;
}

// ---------------- weight transpose+convert ----------------
// w [E][K][N] fp32  ->  wt [E][K/32][N][32] fp16  (wt[e][kb][n][kk] = w[e][kb*32+kk][n])
// Block handles 32k x 64n tile via LDS. Reads and writes fully coalesced.

__global__ __launch_bounds__(256) void transpose_cvt_kernel(
    const float* __restrict__ w, _Float16* __restrict__ wt, int K, int N)
{
    __shared__ float tile[32][68];                   // 68: 16B-aligned rows, pad
    const int e = blockIdx.z, k0 = blockIdx.y * 32, n0 = blockIdx.x * 64;
    const float* src = w + ((size_t)e * K + k0) * N + n0;
    const int t = threadIdx.x;
    #pragma unroll
    for (int f = t; f < 512; f += 256) {             // 512 float4 = 32x64 floats
        int k = f >> 4, nc = (f & 15) * 4;
        *(float4*)&tile[k][nc] = *(const float4*)(src + (size_t)k * N + nc);
    }
    __syncthreads();
    int n = t >> 2, c2 = (t & 3) * 8;
    half8 h;
    #pragma unroll
    for (int q = 0; q < 8; ++q) h[q] = (_Float16)tile[c2 + q][n];
    int KB = K >> 5;
    _Float16* dst = wt + (((size_t)e * KB + (k0 >> 5)) * N + (n0 + n)) * 32 + c2;
    *(half8*)dst = h;
}

// ---------------- GEMM 1: hb = gelu(xg @ wt_fc + b_fc)  (packed in/out) ----------------
// 128x128 tile, BK=32, 4 waves x (4x4 mfma_f32_16x16x32_f16).

__global__ __launch_bounds__(256) void gemm_fc_kernel(
    const _Float16* __restrict__ xg,     // packed [KB_C][NPC][32]
    const _Float16* __restrict__ wt,     // packed [E][KB_C][HDIM][32]
    const float*    __restrict__ b_fc,   // [E][HDIM]
    const int*      __restrict__ tile_expert,
    const int*      __restrict__ mtiles,
    _Float16*       __restrict__ hb)     // packed [KB_H][NPC][32]
{
    const int mt = blockIdx.y;
    if (mt >= *mtiles) return;
    const int nt = blockIdx.x;
    const int e  = tile_expert[mt];
    const int m0 = mt << 7, n0 = nt << 7;

    __shared__ _Float16 As[128 * 32];
    __shared__ _Float16 Bs[128 * 32];

    const int tid = threadIdx.x;
    const int lane = tid & 63, wv = tid >> 6;
    const int wm = (wv >> 1) * 64, wn = (wv & 1) * 64;
    const int l16 = lane & 15, lq = lane >> 4;

    const char* gA0 = (const char*)xg + (size_t)m0 * 64;
    const char* gB0 = (const char*)wt + ((size_t)e * KB_C * HDIM + n0) * 64;
    const int soff = wv * 2048 + lane * 16;
    char* lA = (char*)As + wv * 2048;
    char* lB = (char*)Bs + wv * 2048;

    f32x4 acc[4][4];
    #pragma unroll
    for (int i = 0; i < 4; ++i)
        #pragma unroll
        for (int j = 0; j < 4; ++j) { acc[i][j][0]=0.f; acc[i][j][1]=0.f; acc[i][j][2]=0.f; acc[i][j][3]=0.f; }

    for (int kb = 0; kb < KB_C; ++kb) {
        const char* ga = gA0 + (size_t)kb * (NPC * 64) + soff;
        const char* gb = gB0 + (size_t)kb * (HDIM * 64) + soff;
        ASYNC_CP16(ga,        lA);
        ASYNC_CP16(ga + 1024, lA + 1024);
        ASYNC_CP16(gb,        lB);
        ASYNC_CP16(gb + 1024, lB + 1024);
        __syncthreads();
        half8 af[4], bfv[4];
        #pragma unroll
        for (int i = 0; i < 4; ++i) af[i]  = *(const half8*)&As[(wm + i * 16 + l16) * 32 + lq * 8];
        #pragma unroll
        for (int j = 0; j < 4; ++j) bfv[j] = *(const half8*)&Bs[(wn + j * 16 + l16) * 32 + lq * 8];
        #pragma unroll
        for (int i = 0; i < 4; ++i)
            #pragma unroll
            for (int j = 0; j < 4; ++j)
                acc[i][j] = __builtin_amdgcn_mfma_f32_16x16x32_f16(af[i], bfv[j], acc[i][j], 0, 0, 0);
        __syncthreads();
    }

    float bias[4];
    #pragma unroll
    for (int j = 0; j < 4; ++j) bias[j] = b_fc[e * HDIM + n0 + wn + j * 16 + l16];
    #pragma unroll
    for (int i = 0; i < 4; ++i) {
        #pragma unroll
        for (int r = 0; r < 4; ++r) {
            int slot = m0 + wm + i * 16 + lq * 4 + r;   // D row = quad*4 + reg
            #pragma unroll
            for (int j = 0; j < 4; ++j) {
                int n = n0 + wn + j * 16 + l16;          // D col = lane&15
                float v = gelu_new(acc[i][j][r] + bias[j]);
                hb[((size_t)(n >> 5) * NPC + slot) * 32 + (n & 31)] = (_Float16)v;
            }
        }
    }
}

// ---------------- GEMM 2: y[tok] += gate * (hb @ wt_proj + b_proj), split-K=2 ----------------

__global__ __launch_bounds__(256) void gemm_proj_kernel(
    const _Float16* __restrict__ hb,     // packed [KB_H][NPC][32]
    const _Float16* __restrict__ wt,     // packed [E][KB_H][CDIM][32]
    const float*    __restrict__ b_proj, // [E][CDIM]
    const int*      __restrict__ pair_tok,
    const float*    __restrict__ pair_gate,
    const int*      __restrict__ tile_expert,
    const int*      __restrict__ mtiles,
    float*          __restrict__ y)      // [NTOK][CDIM]
{
    const int mt = blockIdx.y;
    if (mt >= *mtiles) return;
    const int nt = blockIdx.x;
    const int ks = blockIdx.z;           // split-K slice: kb in [ks*64, ks*64+64)
    const int e  = tile_expert[mt];
    const int m0 = mt << 7, n0 = nt << 7;

    __shared__ _Float16 As[128 * 32];
    __shared__ _Float16 Bs[128 * 32];

    const int tid = threadIdx.x;
    const int lane = tid & 63, wv = tid >> 6;
    const int wm = (wv >> 1) * 64, wn = (wv & 1) * 64;
    const int l16 = lane & 15, lq = lane >> 4;

    const char* gA0 = (const char*)hb + (size_t)m0 * 64;
    const char* gB0 = (const char*)wt + ((size_t)e * KB_H * CDIM + n0) * 64;
    const int soff = wv * 2048 + lane * 16;
    char* lA = (char*)As + wv * 2048;
    char* lB = (char*)Bs + wv * 2048;

    f32x4 acc[4][4];
    #pragma unroll
    for (int i = 0; i < 4; ++i)
        #pragma unroll
        for (int j = 0; j < 4; ++j) { acc[i][j][0]=0.f; acc[i][j][1]=0.f; acc[i][j][2]=0.f; acc[i][j][3]=0.f; }

    const int kb_end = ks * 64 + 64;
    for (int kb = ks * 64; kb < kb_end; ++kb) {
        const char* ga = gA0 + (size_t)kb * (NPC * 64) + soff;
        const char* gb = gB0 + (size_t)kb * (CDIM * 64) + soff;
        ASYNC_CP16(ga,        lA);
        ASYNC_CP16(ga + 1024, lA + 1024);
        ASYNC_CP16(gb,        lB);
        ASYNC_CP16(gb + 1024, lB + 1024);
        __syncthreads();
        half8 af[4], bfv[4];
        #pragma unroll
        for (int i = 0; i < 4; ++i) af[i]  = *(const half8*)&As[(wm + i * 16 + l16) * 32 + lq * 8];
        #pragma unroll
        for (int j = 0; j < 4; ++j) bfv[j] = *(const half8*)&Bs[(wn + j * 16 + l16) * 32 + lq * 8];
        #pragma unroll
        for (int i = 0; i < 4; ++i)
            #pragma unroll
            for (int j = 0; j < 4; ++j)
                acc[i][j] = __builtin_amdgcn_mfma_f32_16x16x32_f16(af[i], bfv[j], acc[i][j], 0, 0, 0);
        __syncthreads();
    }

    float bias[4];
    #pragma unroll
    for (int j = 0; j < 4; ++j)
        bias[j] = (ks == 0) ? b_proj[e * CDIM + n0 + wn + j * 16 + l16] : 0.0f;
    #pragma unroll
    for (int i = 0; i < 4; ++i) {
        #pragma unroll
        for (int r = 0; r < 4; ++r) {
            int slot = m0 + wm + i * 16 + lq * 4 + r;
            float g  = pair_gate[slot];
            if (g != 0.0f) {
                int tok = pair_tok[slot];
                float* dst = y + (size_t)tok * CDIM + n0 + wn + l16;
                #pragma unroll
                for (int j = 0; j < 4; ++j)
                    atomicAdd(&dst[j * 16], (acc[i][j][r] + bias[j]) * g);
            }
        }
    }
}

// ---------------- launch ----------------

extern "C" void kernel_launch(void* const* d_in, const int* in_sizes, int n_in,
                              void* d_out, int out_size, void* d_ws, size_t ws_size,
                              hipStream_t stream) {
    const float* x   = (const float*)d_in[0];
    const float* rw  = (const float*)d_in[1];
    const float* wfc = (const float*)d_in[2];
    const float* bfc = (const float*)d_in[3];
    const float* wpj = (const float*)d_in[4];
    const float* bpj = (const float*)d_in[5];
    float* y = (float*)d_out;

    char* ws = (char*)d_ws;
    // workspace layout (bytes), total ~161.7 MB
    _Float16* xg  = (_Float16*)(ws);                    // 18,874,368  [KB_C][NPC][32]
    _Float16* hb  = (_Float16*)(ws + 18874368);         // 75,497,472  [KB_H][NPC][32]
    _Float16* wt  = (_Float16*)(ws + 94371840);         // 67,108,864  shared fc/proj
    char* meta = ws + 161480704;
    int*   pair_tok    = (int*)  (meta);                //  36,864
    float* pair_gate   = (float*)(meta + 36864);        //  36,864
    int*   tok_e       = (int*)  (meta + 73728);        //  32,768
    float* tok_w       = (float*)(meta + 106496);       //  32,768
    int*   counts      = (int*)  (meta + 139264);       // 8
    int*   cursors     = counts + 8;                    // 8
    int*   mtiles      = cursors + 8;                   // 1 (+pad)
    int*   tile_expert = mtiles + 2;                    // 72

    zero_u32<<<36, 256, 0, stream>>>((unsigned int*)pair_tok, NPC);
    zero_u32<<<36, 256, 0, stream>>>((unsigned int*)pair_gate, NPC);
    zero_u32<<<1, 256, 0, stream>>>((unsigned int*)counts, NEXP);
    zero_u32<<<16384, 256, 0, stream>>>((unsigned int*)y, NTOK * CDIM);

    router_kernel<<<1024, 256, 0, stream>>>(x, rw, tok_e, tok_w, counts);
    plan_kernel<<<1, 64, 0, stream>>>(counts, cursors, mtiles, tile_expert);
    assign_kernel<<<16, 256, 0, stream>>>(tok_e, tok_w, cursors, pair_tok, pair_gate);
    gather_x_kernel<<<KB_C * NPC * 4 / 256, 256, 0, stream>>>(x, pair_tok, xg);

    // fc: transpose w_fc -> wt, then GEMM into hb
    transpose_cvt_kernel<<<dim3(HDIM / 64, CDIM / 32, NEXP), 256, 0, stream>>>(wfc, wt, CDIM, HDIM);
    gemm_fc_kernel<<<dim3(HDIM / 128, MAXMT), 256, 0, stream>>>(
        xg, wt, bfc, tile_expert, mtiles, hb);

    // proj: transpose w_proj -> wt (reuse buffer), then GEMM into y
    transpose_cvt_kernel<<<dim3(CDIM / 64, HDIM / 32, NEXP), 256, 0, stream>>>(wpj, wt, HDIM, CDIM);
    gemm_proj_kernel<<<dim3(CDIM / 128, MAXMT, 2), 256, 0, stream>>>(
        hb, wt, bpj, pair_tok, pair_gate, tile_expert, mtiles, y);
}